// Round 5
// baseline (1426.531 us; speedup 1.0000x reference)
//
#include <hip/hip_runtime.h>
#include <cstdio>

typedef unsigned short u16;
typedef unsigned int u32;
typedef unsigned long long u64;
typedef __attribute__((ext_vector_type(8))) short bf16x8;   // 8 x bf16 (4 VGPRs)
typedef __attribute__((ext_vector_type(4))) float f32x4;

#define NWG 64   // v5: 64 WGs x 512 thr -- halves the per-step all-to-all volume

__device__ inline u16 f2bf(float x) {
  union { float f; unsigned u; } v; v.f = x;
  unsigned r = v.u + 0x7FFFu + ((v.u >> 16) & 1u);   // RNE
  return (u16)(r >> 16);
}
__device__ inline float sigm(float x) { return 1.0f / (1.0f + __expf(-x)); }
__device__ inline float tanh_fast(float x) { return 1.0f - 2.0f / (__expf(2.0f * x) + 1.0f); }

// ---------------- fp32 -> bf16 convert (vectorized) ----------------
__global__ __launch_bounds__(256) void k_convert(const float* __restrict__ in,
                                                 u16* __restrict__ out, int n4) {
  int i = blockIdx.x * blockDim.x + threadIdx.x;
  int stride = gridDim.x * blockDim.x;
  const float4* in4 = (const float4*)in;
  ushort4* out4 = (ushort4*)out;
  for (; i < n4; i += stride) {
    float4 v = in4[i];
    ushort4 o; o.x = f2bf(v.x); o.y = f2bf(v.y); o.z = f2bf(v.z); o.w = f2bf(v.w);
    out4[i] = o;
  }
}

// h0 -> h_bf buffer 0 (bf16), zero the packed per-WG flags
__global__ __launch_bounds__(256) void k_init_h(const float* __restrict__ h0,
                                                u16* __restrict__ h_bf,
                                                u32* __restrict__ flags) {
  int i = blockIdx.x * blockDim.x + threadIdx.x;
  if (i < NWG) flags[i] = 0u;          // flag t == "h_t available"
  if (i < 32768) h_bf[i] = f2bf(h0[i]);
}

// [R][C] fp32 -> [C][R] bf16 (tiled transpose)
__global__ __launch_bounds__(256) void k_transpose(const float* __restrict__ in,
                                                   u16* __restrict__ out, int R, int C) {
  __shared__ u16 tile[32][33];
  int tx = threadIdx.x & 31, ty = threadIdx.x >> 5;
  int c = blockIdx.x * 32 + tx;
  for (int i = 0; i < 32; i += 8) {
    int r = blockIdx.y * 32 + ty + i;
    tile[ty + i][tx] = f2bf(in[(size_t)r * C + c]);
  }
  __syncthreads();
  int r = blockIdx.y * 32 + tx;
  for (int i = 0; i < 32; i += 8) {
    int cc = blockIdx.x * 32 + ty + i;
    out[(size_t)cc * R + r] = tile[tx][ty + i];
  }
}

// ---------------- bf16 MFMA GEMM: C[M][N] = A[M][K] * BT[N][K]^T + bias ----------------
__global__ __launch_bounds__(256) void k_gemm_bt(const u16* __restrict__ A,
                                                 const u16* __restrict__ BT,
                                                 const float* __restrict__ bias,
                                                 float* __restrict__ C,
                                                 int M, int N, int K) {
  __shared__ u16 As[128][40];
  __shared__ u16 Bs[128][40];
  const int m0 = blockIdx.y * 128, n0 = blockIdx.x * 128;
  const int tid = threadIdx.x;
  const int lane = tid & 63, wave = tid >> 6;
  const int wm = (wave >> 1) * 64, wn = (wave & 1) * 64;
  const int lm = lane & 15, quad = lane >> 4;
  const int r = tid >> 1, kh = (tid & 1) * 16;

  f32x4 acc[4][4];
  for (int i = 0; i < 4; i++)
    for (int j = 0; j < 4; j++) acc[i][j] = (f32x4){0.f, 0.f, 0.f, 0.f};

  for (int k0 = 0; k0 < K; k0 += 32) {
    const uint4* ap = (const uint4*)(A + (size_t)(m0 + r) * K + k0 + kh);
    uint4 av0 = ap[0], av1 = ap[1];
    const uint4* bp = (const uint4*)(BT + (size_t)(n0 + r) * K + k0 + kh);
    uint4 bv0 = bp[0], bv1 = bp[1];
    __syncthreads();
    *(uint4*)&As[r][kh] = av0; *(uint4*)&As[r][kh + 8] = av1;
    *(uint4*)&Bs[r][kh] = bv0; *(uint4*)&Bs[r][kh + 8] = bv1;
    __syncthreads();
    bf16x8 a_frag[4], b_frag[4];
    for (int i = 0; i < 4; i++) a_frag[i] = *(const bf16x8*)&As[wm + i * 16 + lm][quad * 8];
    for (int j = 0; j < 4; j++) b_frag[j] = *(const bf16x8*)&Bs[wn + j * 16 + lm][quad * 8];
    for (int i = 0; i < 4; i++)
      for (int j = 0; j < 4; j++)
        acc[i][j] = __builtin_amdgcn_mfma_f32_16x16x32_bf16(a_frag[i], b_frag[j], acc[i][j], 0, 0, 0);
  }
  for (int i = 0; i < 4; i++)
    for (int j = 0; j < 4; j++) {
      int row = m0 + wm + i * 16 + quad * 4;
      int col = n0 + wn + j * 16 + lm;
      float bc = bias[col];
      for (int rr = 0; rr < 4; rr++)
        C[(size_t)(row + rr) * N + col] = acc[i][j][rr] + bc;
    }
}

// ---------------- persistent LSTM scan ----------------
// v5: 64 WGs x 512 thr. WG g owns h-cols [16g,16g+16) x 4 gates (64 packed cols).
// Rationale: v1-v4 showed the sync protocol is NOT the limiter (v4's 32x poll
// traffic cut + Hs-drain removal = no change; added MALL transactions in v2/v3
// regressed). Remaining suspect: the h broadcast itself -- NWG x 64 KB of
// agent-scope (L2-bypassing) reads through the MALL per step. Halve NWG to
// halve that volume (8 MB -> 4 MB/step), and halve the sync degree (64 flags).
// To fit: Wh lives entirely in REGISTERS (each of 8 waves owns one 16x16
// output tile; B-fragments = 32 x bf16x8 = 128 VGPRs, loaded once, statically
// indexed). No Whs LDS at all. LDS = h_lds 66 KB + z_buf 8.5 KB.
// Sync protocol = v4 verbatim: agent h stores -> B3 (drain) -> single flag
// store by tid0 -> uniform poll (1 flag per lane now) -> bulk coalesced u64
// broadcast (16/thread). Bitwise-identical MFMA chain order and gate math.
__global__ __launch_bounds__(512) void k_lstm(const float* __restrict__ Z,    // [8192][4096]
                                              const u16* __restrict__ WhT,    // [4096][1024]
                                              const float* __restrict__ c0,   // [32][1024]
                                              u16* __restrict__ h_bf,         // [2][32][1024] bf16
                                              u16* __restrict__ Hs,           // [8192][1024] bf16
                                              float* __restrict__ out_c,
                                              float* __restrict__ out_h,
                                              u32* __restrict__ flags) {
  __shared__ u16 h_lds[32][1032];    // h_t staged (+8 pad), 66 KB
  __shared__ float z_buf[32][66];    // [batch][packed col 0..63], 8.45 KB
  const int g = blockIdx.x;
  const int tid = threadIdx.x;
  const int lane = tid & 63, wave = tid >> 6;
  const int lm = lane & 15, quad = lane >> 4;
  const int mhalf = wave >> 2;       // batch half: rows [16*mhalf, 16*mhalf+16)
  const int nt = wave & 3;           // gate index: packed cols [16*nt, 16*nt+16)
  const int b = tid >> 4, jl = tid & 15;   // gate-math ownership: (b, col 16g+jl)

  // Wh fragments in registers: wave nt, lane (lm,quad) needs Wh col
  // (nt*1024 + 16g + lm), k-offsets quad*8 + 32*ks. One-time load, 128 VGPRs.
  bf16x8 bfr[32];
  {
    const u16* wbase = WhT + (size_t)(nt * 1024 + 16 * g + lm) * 1024 + quad * 8;
#pragma unroll
    for (int ks = 0; ks < 32; ks++)
      bfr[ks] = *(const bf16x8*)(wbase + ks * 32);
  }
  float creg = c0[b * 1024 + 16 * g + jl];

  for (int t = 0; t < 256; t++) {
    // 1. prefetch this step's Z contributions (L2/L3-cached; overlaps the poll)
    size_t zbase = ((size_t)b * 256 + t) * 4096 + 16 * g + jl;
    float z_i = Z[zbase], z_f = Z[zbase + 1024], z_g = Z[zbase + 2048], z_o = Z[zbase + 3072];

    // 2. uniform poll: 64 flags, one per lane, coherent relaxed loads
    {
      const u32 tgt = (u32)t;
      const u32* f0 = flags + lane;
      while (true) {
        u32 v0 = __hip_atomic_load(f0, __ATOMIC_RELAXED, __HIP_MEMORY_SCOPE_AGENT);
        if (__all(v0 >= tgt)) break;
        __builtin_amdgcn_s_sleep(1);
      }
      asm volatile("" ::: "memory");  // no hoisting of h loads above the poll
    }

    // 3. stage h_t -> LDS: 16 coherent u64 loads/thread, perfectly coalesced.
    //    u64 unit u = i*512+tid: batch = 2i + (tid>>8), col = 4*(tid&255).
    {
      const u64* hq = (const u64*)(h_bf + (size_t)(t & 1) * 32768);
      u64 v[16];
#pragma unroll
      for (int i = 0; i < 16; i++)
        v[i] = __hip_atomic_load(hq + i * 512 + tid, __ATOMIC_RELAXED, __HIP_MEMORY_SCOPE_AGENT);
#pragma unroll
      for (int i = 0; i < 16; i++) {
        int bb = 2 * i + (tid >> 8);
        *(u64*)&h_lds[bb][(tid & 255) * 4] = v[i];
      }
    }
    __syncthreads();  // B1: h_lds ready

    // 4. MFMA: wave (mhalf,nt) computes z[16*mhalf..+16][16*nt..+16], K=1024,
    //    4 ILP chains, B-operand from registers (bfr), A from LDS.
    const u16* arow = &h_lds[mhalf * 16 + lm][quad * 8];
    f32x4 a0 = (f32x4){0.f, 0.f, 0.f, 0.f}, a1 = a0, a2 = a0, a3 = a0;
#pragma unroll
    for (int ks = 0; ks < 32; ks += 4) {
      bf16x8 af0 = *(const bf16x8*)(arow + (ks + 0) * 32);
      bf16x8 af1 = *(const bf16x8*)(arow + (ks + 1) * 32);
      bf16x8 af2 = *(const bf16x8*)(arow + (ks + 2) * 32);
      bf16x8 af3 = *(const bf16x8*)(arow + (ks + 3) * 32);
      a0 = __builtin_amdgcn_mfma_f32_16x16x32_bf16(af0, bfr[ks + 0], a0, 0, 0, 0);
      a1 = __builtin_amdgcn_mfma_f32_16x16x32_bf16(af1, bfr[ks + 1], a1, 0, 0, 0);
      a2 = __builtin_amdgcn_mfma_f32_16x16x32_bf16(af2, bfr[ks + 2], a2, 0, 0, 0);
      a3 = __builtin_amdgcn_mfma_f32_16x16x32_bf16(af3, bfr[ks + 3], a3, 0, 0, 0);
    }
    f32x4 accs = (a0 + a1) + (a2 + a3);
    for (int rr = 0; rr < 4; rr++)
      z_buf[mhalf * 16 + quad * 4 + rr][nt * 16 + lm] = accs[rr];
    __syncthreads();  // B2: z_buf ready

    // 5. gate math: thread (b, jl) owns (batch b, h-col 16g+jl)
    float zi = z_buf[b][jl]      + z_i;
    float zf = z_buf[b][16 + jl] + z_f;
    float zg = z_buf[b][32 + jl] + z_g;
    float zo = z_buf[b][48 + jl] + z_o;
    float ig = sigm(zi), fg = sigm(zf), gg = tanh_fast(zg), og = sigm(zo);
    creg = fg * creg + ig * gg;
    float hv = og * tanh_fast(creg);
    u16 hb = f2bf(hv);
    // publish h write-through to the coherence point (no L2 residency)
    __hip_atomic_store(h_bf + (size_t)((t + 1) & 1) * 32768 + b * 1024 + 16 * g + jl,
                       hb, __ATOMIC_RELAXED, __HIP_MEMORY_SCOPE_AGENT);
    __syncthreads();  // B3: vmcnt drain -> all h stores at the coherence point
    if (tid == 0)
      __hip_atomic_store(flags + g, (u32)(t + 1),
                         __ATOMIC_RELAXED, __HIP_MEMORY_SCOPE_AGENT);

    // off the critical path: history store (+ final c/h at t=255) AFTER publish
    __builtin_nontemporal_store(hb, Hs + ((size_t)b * 256 + t) * 1024 + 16 * g + jl);
    if (t == 255) {
      out_c[b * 1024 + 16 * g + jl] = creg;
      out_h[b * 1024 + 16 * g + jl] = hv;
    }
  }
}

extern "C" void kernel_launch(void* const* d_in, const int* in_sizes, int n_in,
                              void* d_out, int out_size, void* d_ws, size_t ws_size,
                              hipStream_t stream) {
  const float* c0   = (const float*)d_in[0];
  const float* h0   = (const float*)d_in[1];
  const float* X    = (const float*)d_in[2];   // [32,256,1024]
  const float* Wi   = (const float*)d_in[3];   // [1024][4096]
  const float* Wh   = (const float*)d_in[4];   // [1024][4096]
  const float* bias = (const float*)d_in[5];   // [4096]
  const float* Wd   = (const float*)d_in[6];   // [1024][1024]
  const float* bd   = (const float*)d_in[7];   // [1024]
  float* out   = (float*)d_out;
  float* out_c = out;
  float* out_h = out + 32768;
  float* out_x = out + 65536;

  char* ws = (char*)d_ws;
  size_t off = 0;
  auto alloc = [&](size_t bytes) { char* p = ws + off; off += (bytes + 255) & ~255ull; return p; };
  float* Z     = (float*)alloc(134217728ull);   // [8192][4096] fp32
  u16*   Xb    = (u16*)alloc(16777216ull);      // [8192][1024] bf16
  u16*   WiT   = (u16*)alloc(8388608ull);       // [4096][1024] bf16
  u16*   WhT   = (u16*)alloc(8388608ull);       // [4096][1024] bf16
  u16*   WdT   = (u16*)alloc(2097152ull);       // [1024][1024] bf16
  u16*   Hs    = (u16*)alloc(16777216ull);      // [8192][1024] bf16
  u16*   h_bf  = (u16*)alloc(131072ull);        // [2][32][1024] bf16
  u32*   flags = (u32*)alloc(NWG * 4);
  if (off > ws_size) {
    fprintf(stderr, "WS too small: need %zu have %zu\n", off, ws_size);
    return;
  }

  k_convert<<<2048, 256, 0, stream>>>(X, Xb, 8388608 / 4);
  k_init_h<<<128, 256, 0, stream>>>(h0, h_bf, flags);
  k_transpose<<<dim3(128, 32), 256, 0, stream>>>(Wi, WiT, 1024, 4096);
  k_transpose<<<dim3(128, 32), 256, 0, stream>>>(Wh, WhT, 1024, 4096);
  k_transpose<<<dim3(32, 32), 256, 0, stream>>>(Wd, WdT, 1024, 1024);
  k_gemm_bt<<<dim3(32, 64), 256, 0, stream>>>(Xb, WiT, bias, Z, 8192, 4096, 1024);
  k_lstm<<<NWG, 512, 0, stream>>>(Z, WhT, c0, h_bf, Hs, out_c, out_h, flags);
  k_gemm_bt<<<dim3(8, 64), 256, 0, stream>>>(Hs, WdT, bd, out_x, 8192, 1024, 1024);
}